// Round 19
// baseline (260.623 us; speedup 1.0000x reference)
//
#include <hip/hip_runtime.h>

#define N_NODES 100000
#define N_EDGES 1200000
#define IN_F 128
#define HID 64
#define BN_EPS 1e-5f
#define E4 (N_EDGES / 4)
#define NBKT 391       // ceil(100000/256) buckets; bucket = dst >> 8
#define BSLOT 4096     // slots per bucket region
#define NBB 293        // bucket-scatter blocks (4096 edges each, 512 threads)
#define SB 406         // stats_in virtual blocks (512 threads, 16 rows/round)
#define GEMM_B 1563    // ceil(100000/64)
#define GT_B 782       // ceil(100000/128) for 128-row gemm_t

typedef unsigned int uint;
typedef unsigned short ushort;
typedef __attribute__((ext_vector_type(8))) short bf16x8;
typedef __attribute__((ext_vector_type(4))) float f32x4;

__device__ inline uint f2bf(float f) {        // f32 -> bf16 (RNE), low 16 bits
    uint u = __float_as_uint(f);
    return (u + 0x7fffu + ((u >> 16) & 1u)) >> 16;
}
__device__ inline float bflo(uint v) { return __uint_as_float(v << 16); }
__device__ inline float bfhi(uint v) { return __uint_as_float(v & 0xffff0000u); }

union U4B8 { uint4 u; bf16x8 b; };

// ---------------- K_B (512 thr): bucket scatter || stats(x)+xb || Wt prep ----------------
__global__ __launch_bounds__(512) void k_bucket_stats(
    const int4* __restrict__ src4, const int4* __restrict__ dst4,
    int* __restrict__ cursor, int* __restrict__ pairs,
    const float4* __restrict__ x4, uint2* __restrict__ xb2, float* __restrict__ sums,
    const float* __restrict__ W0, const float* __restrict__ Ws,
    ushort* __restrict__ wtg) {
    int t = threadIdx.x;
    if (blockIdx.x < NBB) {
        __shared__ int cnt_l[NBKT];
        __shared__ int base_l[NBKT];
        for (int i = t; i < NBKT; i += 512) cnt_l[i] = 0;
        __syncthreads();
        int4 d[2];
        int bk[8], rk[8];
#pragma unroll
        for (int k = 0; k < 2; k++) {
            int idx = blockIdx.x * 1024 + k * 512 + t;
            if (idx < E4) {
                int4 dv = dst4[idx];
                d[k] = dv;
                bk[k * 4 + 0] = dv.x >> 8;
                bk[k * 4 + 1] = dv.y >> 8;
                bk[k * 4 + 2] = dv.z >> 8;
                bk[k * 4 + 3] = dv.w >> 8;
                rk[k * 4 + 0] = atomicAdd(&cnt_l[bk[k * 4 + 0]], 1);
                rk[k * 4 + 1] = atomicAdd(&cnt_l[bk[k * 4 + 1]], 1);
                rk[k * 4 + 2] = atomicAdd(&cnt_l[bk[k * 4 + 2]], 1);
                rk[k * 4 + 3] = atomicAdd(&cnt_l[bk[k * 4 + 3]], 1);
            }
        }
        __syncthreads();
        for (int i = t; i < NBKT; i += 512) {
            int c = cnt_l[i];
            base_l[i] = c ? atomicAdd(&cursor[i], c) : 0;
        }
        __syncthreads();
#pragma unroll
        for (int k = 0; k < 2; k++) {
            int idx = blockIdx.x * 1024 + k * 512 + t;
            if (idx < E4) {
                int4 sv = src4[idx];
                int b0 = bk[k * 4 + 0], b1 = bk[k * 4 + 1];
                int b2 = bk[k * 4 + 2], b3 = bk[k * 4 + 3];
                pairs[b0 * BSLOT + base_l[b0] + rk[k * 4 + 0]] = sv.x | ((d[k].x & 255) << 24);
                pairs[b1 * BSLOT + base_l[b1] + rk[k * 4 + 1]] = sv.y | ((d[k].y & 255) << 24);
                pairs[b2 * BSLOT + base_l[b2] + rk[k * 4 + 2]] = sv.z | ((d[k].z & 255) << 24);
                pairs[b3 * BSLOT + base_l[b3] + rk[k * 4 + 3]] = sv.w | ((d[k].w & 255) << 24);
            }
        }
        return;
    }
    if (blockIdx.x >= NBB + SB) {
        // Wt prep, FRAGMENT-MAJOR: slot ((c*4+nt)*64 + lane)*8 + j holds
        // bf16(W[k= c*32+(lane>>4)*8+j][n= nt*16+(lane&15)]).
        for (int i = t; i < 8192; i += 512) {
            int j = i & 7, l = (i >> 3) & 63, f = i >> 9;
            int c = f >> 2, nt = f & 3, lr = l & 15, lg = l >> 4;
            int k = c * 32 + lg * 8 + j, n = nt * 16 + lr;
            wtg[i] = (ushort)f2bf(W0[k * 64 + n]);
        }
#pragma unroll
        for (int li = 0; li < 3; li++) {
            const float* Wl = Ws + li * 4096;
            ushort* wt = wtg + 8192 + li * 4096;
            for (int i = t; i < 4096; i += 512) {
                int j = i & 7, l = (i >> 3) & 63, f = i >> 9;  // f 0..7
                int c = f >> 2, nt = f & 3, lr = l & 15, lg = l >> 4;
                int k = c * 32 + lg * 8 + j, n = nt * 16 + lr;
                wt[i] = (ushort)f2bf(Wl[k * 64 + n]);
            }
        }
        return;
    }
    // ---- stats(x) + x->bf16 path (512 thr: 16 rows/round) ----
    __shared__ float lds[8][32][8];
    int vb = blockIdx.x - NBB;
    int cq = t & 31, rs = t >> 5;
    float s1[4] = {0.f, 0.f, 0.f, 0.f}, s2[4] = {0.f, 0.f, 0.f, 0.f};
    for (int row = vb * 16 + rs; row < N_NODES; row += SB * 16) {
        float4 v = x4[(size_t)row * 32 + cq];
        s1[0] += v.x; s2[0] += v.x * v.x;
        s1[1] += v.y; s2[1] += v.y * v.y;
        s1[2] += v.z; s2[2] += v.z * v.z;
        s1[3] += v.w; s2[3] += v.w * v.w;
        uint2 p;
        p.x = f2bf(v.x) | (f2bf(v.y) << 16);
        p.y = f2bf(v.z) | (f2bf(v.w) << 16);
        xb2[(size_t)row * 32 + cq] = p;
    }
#pragma unroll
    for (int j = 0; j < 4; j++) {
        s1[j] += __shfl_xor(s1[j], 32);
        s2[j] += __shfl_xor(s2[j], 32);
    }
    int w = t >> 6;
    if ((t & 63) < 32) {
#pragma unroll
        for (int j = 0; j < 4; j++) {
            lds[w][cq][j] = s1[j];
            lds[w][cq][4 + j] = s2[j];
        }
    }
    __syncthreads();
    if (t < 256) {
        int cq2 = t >> 3, k = t & 7;
        float v = 0.f;
#pragma unroll
        for (int ww = 0; ww < 8; ww++) v += lds[ww][cq2][k];
        int col = cq2 * 4 + (k & 3);
        atomicAdd(&sums[(k >> 2) * 128 + col], v);
    }
}

// ---------------- tiny scan over 391 bucket totals ----------------
__global__ __launch_bounds__(512) void k_scan_bkt(const int* __restrict__ cursor,
                                                  int* __restrict__ bucketBase,
                                                  int* __restrict__ row_ptr) {
    __shared__ int sb[512];
    int t = threadIdx.x;
    int v = (t < NBKT) ? cursor[t] : 0;
    sb[t] = v;
    __syncthreads();
    int x = v;
    for (int off = 1; off < 512; off <<= 1) {
        int y = (t >= off) ? sb[t - off] : 0;
        __syncthreads();
        x += y;
        sb[t] = x;
        __syncthreads();
    }
    if (t <= NBKT) bucketBase[t] = x - v;
    if (t == 0) row_ptr[N_NODES] = N_EDGES;
}

// ---------------- k_csr: per-bucket CSR finalize ----------------
__global__ __launch_bounds__(256) void k_csr(
    const int* __restrict__ pairs, const int* __restrict__ cursor,
    const int* __restrict__ bucketBase, int* __restrict__ row_ptr,
    float* __restrict__ dinv, int* __restrict__ col) {
    __shared__ int cnt_l[256];
    __shared__ int sb[256];
    __shared__ int sbex[256];
    int b = blockIdx.x;
    int t = threadIdx.x;
    int n = cursor[b];
    int base = bucketBase[b];
    const int* reg = pairs + (size_t)b * BSLOT;
    cnt_l[t] = 0;
    __syncthreads();
    int rk[16];
#pragma unroll
    for (int k = 0; k < 16; k++) {
        int e = k * 256 + t;
        if (e < n) {
            int p = reg[e];
            rk[k] = atomicAdd(&cnt_l[(uint)p >> 24], 1);
        }
    }
    __syncthreads();
    int c = cnt_l[t];
    sb[t] = c;
    __syncthreads();
    int x2 = c;
    for (int off = 1; off < 256; off <<= 1) {
        int y = (t >= off) ? sb[t - off] : 0;
        __syncthreads();
        x2 += y;
        sb[t] = x2;
        __syncthreads();
    }
    sbex[t] = x2 - c;
    int i = b * 256 + t;
    if (i < N_NODES) {
        dinv[i] = rsqrtf((float)(c + 1));
        row_ptr[i] = base + x2 - c;
    }
    __syncthreads();
#pragma unroll
    for (int k = 0; k < 16; k++) {
        int e = k * 256 + t;
        if (e < n) {
            int p = reg[e];
            col[base + sbex[(uint)p >> 24] + rk[k]] = p & 0xFFFFFF;
        }
    }
}

// ---------------- k_gemm0: BN(xb)@W0+bias, relu -> h0 bf16 ----------------
__global__ __launch_bounds__(256, 4) void k_gemm0(
    const ushort* __restrict__ xb, const ushort* __restrict__ wt0,
    const float* __restrict__ sums, const float* __restrict__ gamma,
    const float* __restrict__ beta, const float* __restrict__ bias,
    ushort* __restrict__ h0) {
    __shared__ float scale_s[IN_F], shift_s[IN_F];
    __shared__ ushort rep[4][1024];
    int t = threadIdx.x;
    int bid = blockIdx.x;
    if (t < IN_F) {
        float m = sums[t] * (1.0f / N_NODES);
        float var = sums[IN_F + t] * (1.0f / N_NODES) - m * m;
        float sc = gamma[t] * rsqrtf(var + BN_EPS);
        scale_s[t] = sc;
        shift_s[t] = beta[t] - m * sc;
    }
    __syncthreads();
    int w = t >> 6, l = t & 63, lr = l & 15, lg = l >> 4;
    int row = bid * 64 + w * 16 + lr;
    if (row >= N_NODES) row = N_NODES - 1;
    const ushort* xr = xb + (size_t)row * 128;
    uint4 av[4];
#pragma unroll
    for (int c = 0; c < 4; c++)
        av[c] = *(const uint4*)(xr + c * 32 + lg * 8);
    bf16x8 Bf[4][4];
#pragma unroll
    for (int c = 0; c < 4; c++)
#pragma unroll
        for (int nt = 0; nt < 4; nt++)
            Bf[c][nt] = *(const bf16x8*)(wt0 + ((c * 4 + nt) * 64 + l) * 8);
    bf16x8 af[4];
#pragma unroll
    for (int c = 0; c < 4; c++) {
        int k0 = c * 32 + lg * 8;
        float4 sc0 = *(const float4*)(scale_s + k0);
        float4 sc1 = *(const float4*)(scale_s + k0 + 4);
        float4 sh0 = *(const float4*)(shift_s + k0);
        float4 sh1 = *(const float4*)(shift_s + k0 + 4);
        U4B8 cvt;
        cvt.u.x = f2bf(bflo(av[c].x) * sc0.x + sh0.x) | (f2bf(bfhi(av[c].x) * sc0.y + sh0.y) << 16);
        cvt.u.y = f2bf(bflo(av[c].y) * sc0.z + sh0.z) | (f2bf(bfhi(av[c].y) * sc0.w + sh0.w) << 16);
        cvt.u.z = f2bf(bflo(av[c].z) * sc1.x + sh1.x) | (f2bf(bfhi(av[c].z) * sc1.y + sh1.y) << 16);
        cvt.u.w = f2bf(bflo(av[c].w) * sc1.z + sh1.z) | (f2bf(bfhi(av[c].w) * sc1.w + sh1.w) << 16);
        af[c] = cvt.b;
    }
    f32x4 acc[4];
#pragma unroll
    for (int nt = 0; nt < 4; nt++) acc[nt] = (f32x4){0.f, 0.f, 0.f, 0.f};
#pragma unroll
    for (int c = 0; c < 4; c++)
#pragma unroll
        for (int nt = 0; nt < 4; nt++)
            acc[nt] = __builtin_amdgcn_mfma_f32_16x16x32_bf16(af[c], Bf[c][nt], acc[nt], 0, 0, 0);

    int wrow0 = bid * 64 + w * 16;
    ushort* myA = rep[w];
    float bias_v[4];
#pragma unroll
    for (int nt = 0; nt < 4; nt++) bias_v[nt] = bias[nt * 16 + lr];
#pragma unroll
    for (int nt = 0; nt < 4; nt++) {
#pragma unroll
        for (int r = 0; r < 4; r++) {
            float v = fmaxf(acc[nt][r] + bias_v[nt], 0.f);
            int rowl = lg * 4 + r;
            int byte = (rowl * 128 + (nt * 16 + lr) * 2) ^ ((rowl & 7) << 4);
            *(ushort*)((char*)myA + byte) = (ushort)f2bf(v);
        }
    }
    {
        int rowl0 = l >> 3, kg0 = l & 7;
        int b0 = (rowl0 * 128 + kg0 * 16) ^ ((rowl0 & 7) << 4);
        int rowl1 = 8 + rowl0;
        int b1 = (rowl1 * 128 + kg0 * 16) ^ ((rowl1 & 7) << 4);
        uint4 v0 = *(uint4*)((char*)myA + b0);
        uint4 v1 = *(uint4*)((char*)myA + b1);
        size_t gg = (size_t)wrow0 * 128 + l * 16;
        if (wrow0 + rowl0 < N_NODES) *(uint4*)((char*)h0 + gg) = v0;
        if (wrow0 + rowl1 < N_NODES) *(uint4*)((char*)h0 + gg + 1024) = v1;
    }
}

// ---------------- k_gemm_t: 128 rows/block; t = (BN(h)@W)*dinv bf16 ----------------
__global__ __launch_bounds__(256, 4) void k_gemm_t(
    const ushort* __restrict__ h, const ushort* __restrict__ wt,
    const float* __restrict__ sums, const float* __restrict__ gamma,
    const float* __restrict__ beta, const float* __restrict__ dinv,
    ushort* __restrict__ out) {
    __shared__ float scale_s[HID], shift_s[HID];
    __shared__ ushort rep[4][1024];
    int t = threadIdx.x;
    if (t < HID) {
        float m = sums[t] * (1.0f / N_NODES);
        float var = sums[HID + t] * (1.0f / N_NODES) - m * m;
        float sc = gamma[t] * rsqrtf(var + BN_EPS);
        scale_s[t] = sc;
        shift_s[t] = beta[t] - m * sc;
    }
    __syncthreads();
    int w = t >> 6, l = t & 63, lr = l & 15, lg = l >> 4;
    int bid = blockIdx.x;
    int row0 = bid * 128 + w * 16 + lr;
    int row1 = row0 + 64;
    if (row0 >= N_NODES) row0 = N_NODES - 1;
    if (row1 >= N_NODES) row1 = N_NODES - 1;
    uint4 av0[2], av1[2];
#pragma unroll
    for (int c = 0; c < 2; c++) {
        av0[c] = *(const uint4*)(h + (size_t)row0 * 64 + c * 32 + lg * 8);
        av1[c] = *(const uint4*)(h + (size_t)row1 * 64 + c * 32 + lg * 8);
    }
    bf16x8 Bf[2][4];
#pragma unroll
    for (int c = 0; c < 2; c++)
#pragma unroll
        for (int nt = 0; nt < 4; nt++)
            Bf[c][nt] = *(const bf16x8*)(wt + ((c * 4 + nt) * 64 + l) * 8);
    bf16x8 af0[2], af1[2];
#pragma unroll
    for (int c = 0; c < 2; c++) {
        int k0 = c * 32 + lg * 8;
        float4 sc0 = *(const float4*)(scale_s + k0);
        float4 sc1 = *(const float4*)(scale_s + k0 + 4);
        float4 sh0 = *(const float4*)(shift_s + k0);
        float4 sh1 = *(const float4*)(shift_s + k0 + 4);
        U4B8 c0, c1;
        c0.u.x = f2bf(bflo(av0[c].x) * sc0.x + sh0.x) | (f2bf(bfhi(av0[c].x) * sc0.y + sh0.y) << 16);
        c0.u.y = f2bf(bflo(av0[c].y) * sc0.z + sh0.z) | (f2bf(bfhi(av0[c].y) * sc0.w + sh0.w) << 16);
        c0.u.z = f2bf(bflo(av0[c].z) * sc1.x + sh1.x) | (f2bf(bfhi(av0[c].z) * sc1.y + sh1.y) << 16);
        c0.u.w = f2bf(bflo(av0[c].w) * sc1.z + sh1.z) | (f2bf(bfhi(av0[c].w) * sc1.w + sh1.w) << 16);
        af0[c] = c0.b;
        c1.u.x = f2bf(bflo(av1[c].x) * sc0.x + sh0.x) | (f2bf(bfhi(av1[c].x) * sc0.y + sh0.y) << 16);
        c1.u.y = f2bf(bflo(av1[c].y) * sc0.z + sh0.z) | (f2bf(bfhi(av1[c].y) * sc0.w + sh0.w) << 16);
        c1.u.z = f2bf(bflo(av1[c].z) * sc1.x + sh1.x) | (f2bf(bfhi(av1[c].z) * sc1.y + sh1.y) << 16);
        c1.u.w = f2bf(bflo(av1[c].w) * sc1.z + sh1.z) | (f2bf(bfhi(av1[c].w) * sc1.w + sh1.w) << 16);
        af1[c] = c1.b;
    }
    f32x4 acc0[4], acc1[4];
#pragma unroll
    for (int nt = 0; nt < 4; nt++) {
        acc0[nt] = (f32x4){0.f, 0.f, 0.f, 0.f};
        acc1[nt] = (f32x4){0.f, 0.f, 0.f, 0.f};
    }
#pragma unroll
    for (int c = 0; c < 2; c++)
#pragma unroll
        for (int nt = 0; nt < 4; nt++) {
            acc0[nt] = __builtin_amdgcn_mfma_f32_16x16x32_bf16(af0[c], Bf[c][nt], acc0[nt], 0, 0, 0);
            acc1[nt] = __builtin_amdgcn_mfma_f32_16x16x32_bf16(af1[c], Bf[c][nt], acc1[nt], 0, 0, 0);
        }
    ushort* myA = rep[w];
#pragma unroll
    for (int s = 0; s < 2; s++) {
        int wrow0 = bid * 128 + s * 64 + w * 16;
        f32x4* acc = s ? acc1 : acc0;
        int dbase = wrow0 + lg * 4;
        if (dbase > N_NODES - 4) dbase = N_NODES - 4;
        float4 dv = *(const float4*)(dinv + dbase);
        float dvv[4] = {dv.x, dv.y, dv.z, dv.w};
#pragma unroll
        for (int nt = 0; nt < 4; nt++) {
#pragma unroll
            for (int r = 0; r < 4; r++) {
                float v = acc[nt][r] * dvv[r];
                int rowl = lg * 4 + r;
                int byte = (rowl * 128 + (nt * 16 + lr) * 2) ^ ((rowl & 7) << 4);
                *(ushort*)((char*)myA + byte) = (ushort)f2bf(v);
            }
        }
        int rowl0 = l >> 3, kg0 = l & 7;
        int b0 = (rowl0 * 128 + kg0 * 16) ^ ((rowl0 & 7) << 4);
        int rowl1 = 8 + rowl0;
        int b1 = (rowl1 * 128 + kg0 * 16) ^ ((rowl1 & 7) << 4);
        uint4 v0 = *(uint4*)((char*)myA + b0);
        uint4 v1 = *(uint4*)((char*)myA + b1);
        size_t gg = (size_t)wrow0 * 128 + l * 16;
        if (wrow0 + rowl0 < N_NODES) *(uint4*)((char*)out + gg) = v0;
        if (wrow0 + rowl1 < N_NODES) *(uint4*)((char*)out + gg + 1024) = v1;
    }
}

// ---------------- stats on bf16 h (C=64) ----------------
__global__ __launch_bounds__(256) void k_stats_h(const uint4* __restrict__ h4,
                                                 float* __restrict__ sums) {
    __shared__ float lds[4][8][16];
    int t = threadIdx.x;
    int cg = t & 7, rs = t >> 3;
    float s1[8], s2[8];
#pragma unroll
    for (int j = 0; j < 8; j++) { s1[j] = 0.f; s2[j] = 0.f; }
    for (int r = blockIdx.x * 32 + rs; r < N_NODES; r += gridDim.x * 32) {
        uint4 v = h4[(size_t)r * 8 + cg];
        float f;
        f = bflo(v.x); s1[0] += f; s2[0] += f * f;
        f = bfhi(v.x); s1[1] += f; s2[1] += f * f;
        f = bflo(v.y); s1[2] += f; s2[2] += f * f;
        f = bfhi(v.y); s1[3] += f; s2[3] += f * f;
        f = bflo(v.z); s1[4] += f; s2[4] += f * f;
        f = bfhi(v.z); s1[5] += f; s2[5] += f * f;
        f = bflo(v.w); s1[6] += f; s2[6] += f * f;
        f = bfhi(v.w); s1[7] += f; s2[7] += f * f;
    }
#pragma unroll
    for (int off = 8; off <= 32; off <<= 1) {
#pragma unroll
        for (int j = 0; j < 8; j++) {
            s1[j] += __shfl_xor(s1[j], off);
            s2[j] += __shfl_xor(s2[j], off);
        }
    }
    int w = t >> 6;
    if ((t & 63) < 8) {
#pragma unroll
        for (int j = 0; j < 8; j++) {
            lds[w][cg][j] = s1[j];
            lds[w][cg][8 + j] = s2[j];
        }
    }
    __syncthreads();
    if (t < 128) {
        int cg2 = t >> 4, k = t & 15;
        float v = lds[0][cg2][k] + lds[1][cg2][k] + lds[2][cg2][k] + lds[3][cg2][k];
        int col = cg2 * 8 + (k & 7);
        atomicAdd(&sums[(k >> 3) * 64 + col], v);
    }
}

// ---------------- per-node gather aggregation (4 groups x 16 lanes x uint2, 16 edges/iter) ----------------
template <bool OUT_BF16>
__global__ __launch_bounds__(256) void k_agg(const uint2* __restrict__ t2,
                                             const int* __restrict__ row_ptr,
                                             const int* __restrict__ col,
                                             const float* __restrict__ dinv,
                                             const float* __restrict__ bias,
                                             void* __restrict__ out) {
    int wid = (blockIdx.x * 256 + threadIdx.x) >> 6;
    int lane = threadIdx.x & 63;
    int g = lane >> 4, q = lane & 15;    // 4 groups of 16 lanes; lane holds 4 bf16 (8B)
    if (wid >= N_NODES) return;
    int e0 = row_ptr[wid], e1 = row_ptr[wid + 1];
    int deg = e1 - e0;
    int ce = e0 + lane;
    int cidx = __builtin_nontemporal_load(col + ((ce < e1) ? ce : 0));  // 64 edges, NT (keep L2 for t2)
    float a[4] = {0.f, 0.f, 0.f, 0.f};
    uint2 selfv = {0, 0};
    if (g == 0) selfv = t2[(size_t)wid * 16 + q];
    int degc = deg < 64 ? deg : 64;
    // 16 edges per iteration: 4 gathers in flight per lane; deg<=16 -> 1 iter
    for (int d = 0; d < degc; d += 16) {
        int i0 = d + g, i1 = d + 4 + g, i2 = d + 8 + g, i3 = d + 12 + g;
        int s0 = __shfl(cidx, i0 & 63);
        int s1 = __shfl(cidx, i1 & 63);
        int s2 = __shfl(cidx, i2 & 63);
        int s3 = __shfl(cidx, i3 & 63);
        bool k0 = i0 < degc, k1 = i1 < degc, k2 = i2 < degc, k3 = i3 < degc;
        uint2 v0 = t2[(size_t)(k0 ? s0 : wid) * 16 + q];
        uint2 v1 = t2[(size_t)(k1 ? s1 : wid) * 16 + q];
        uint2 v2 = t2[(size_t)(k2 ? s2 : wid) * 16 + q];
        uint2 v3 = t2[(size_t)(k3 ? s3 : wid) * 16 + q];
        if (k0) {
            a[0] += bflo(v0.x); a[1] += bfhi(v0.x);
            a[2] += bflo(v0.y); a[3] += bfhi(v0.y);
        }
        if (k1) {
            a[0] += bflo(v1.x); a[1] += bfhi(v1.x);
            a[2] += bflo(v1.y); a[3] += bfhi(v1.y);
        }
        if (k2) {
            a[0] += bflo(v2.x); a[1] += bfhi(v2.x);
            a[2] += bflo(v2.y); a[3] += bfhi(v2.y);
        }
        if (k3) {
            a[0] += bflo(v3.x); a[1] += bfhi(v3.x);
            a[2] += bflo(v3.y); a[3] += bfhi(v3.y);
        }
    }
    for (int base = e0 + 64; base < e1; base += 4) {   // deg>64 tail (rare)
        int ee = base + g;
        if (ee < e1) {
            int s = col[ee];
            uint2 v = t2[(size_t)s * 16 + q];
            a[0] += bflo(v.x); a[1] += bfhi(v.x);
            a[2] += bflo(v.y); a[3] += bfhi(v.y);
        }
    }
    if (g == 0) {
        a[0] += bflo(selfv.x); a[1] += bfhi(selfv.x);
        a[2] += bflo(selfv.y); a[3] += bfhi(selfv.y);
    }
    // fold 4 groups -> group 0 (2 rounds, 4 values each)
#pragma unroll
    for (int off = 16; off <= 32; off <<= 1) {
#pragma unroll
        for (int j = 0; j < 4; j++) a[j] += __shfl_xor(a[j], off);
    }
    if (g == 0) {
        float di = dinv[wid];
        float4 b4 = reinterpret_cast<const float4*>(bias)[q];
        float r0 = fmaxf(di * a[0] + b4.x, 0.f);
        float r1 = fmaxf(di * a[1] + b4.y, 0.f);
        float r2 = fmaxf(di * a[2] + b4.z, 0.f);
        float r3 = fmaxf(di * a[3] + b4.w, 0.f);
        if (OUT_BF16) {
            uint2 o;
            o.x = f2bf(r0) | (f2bf(r1) << 16);
            o.y = f2bf(r2) | (f2bf(r3) << 16);
            ((uint2*)out)[(size_t)wid * 16 + q] = o;
        } else {
            ((float4*)out)[(size_t)wid * 16 + q] = (float4){r0, r1, r2, r3};
        }
    }
}

// ---------------- launch ----------------

extern "C" void kernel_launch(void* const* d_in, const int* in_sizes, int n_in,
                              void* d_out, int out_size, void* d_ws, size_t ws_size,
                              hipStream_t stream) {
    const float* x = (const float*)d_in[0];
    const int* ei = (const int*)d_in[1];
    const int4* src4 = (const int4*)ei;
    const int4* dst4 = (const int4*)(ei + N_EDGES);
    const float* bn0_g = (const float*)d_in[2];
    const float* bn0_b = (const float*)d_in[3];
    const float* W0 = (const float*)d_in[4];
    const float* b0 = (const float*)d_in[5];
    const float* bns_g = (const float*)d_in[6];
    const float* bns_b = (const float*)d_in[7];
    const float* Ws = (const float*)d_in[8];
    const float* bs = (const float*)d_in[9];
    float* out = (float*)d_out;
    char* ws = (char*)d_ws;

    // workspace layout (bytes); xb dead after k_gemm0 -> h1 and tbuf alias its halves
    float*  dinv    = (float*)(ws + 0);          //   400,128
    int*    row_ptr = (int*)(ws + 400128);       //   400,384
    int*    col     = (int*)(ws + 800512);       // 4,800,000
    int*    cursor  = (int*)(ws + 5600512);      //     1,600
    float*  sums    = (float*)(ws + 5602112);    //     2,560
    int*    bktBase = (int*)(ws + 5604672);      //     1,600
    ushort* wtg     = (ushort*)(ws + 5606272);   //    40,960
    int*    pairs   = (int*)(ws + 5647232);      //  6,406,144
    ushort* h0      = (ushort*)(ws + 12053376);  // 12,800,000
    ushort* xb      = (ushort*)(ws + 24853376);  // 25,600,000
    ushort* h1      = (ushort*)(ws + 24853376);  // 12,800,000 (aliases xb lower half)
    ushort* tbuf    = (ushort*)(ws + 37653376);  // 12,800,000 (aliases xb upper half) -> 50.5MB
    ushort* h2      = h0;                        // h0 dead after gemm_t1
    float* sums0 = sums;          // 256 floats (IN_F)
    float* sums1 = sums + 256;    // 128
    float* sums2 = sums + 384;    // 128
    float* sums3 = sums + 512;    // 128
    const ushort* wt1 = wtg + 8192;
    const ushort* wt2 = wtg + 8192 + 4096;
    const ushort* wt3 = wtg + 8192 + 8192;

    const int AGG_B = (N_NODES + 3) / 4;      // 25000

    hipMemsetAsync(cursor, 0, 1600 + 640 * sizeof(float), stream);

    // ---- K_B (512 thr): bucket scatter || stats(x)+xb || Wt prep ----
    k_bucket_stats<<<NBB + SB + 1, 512, 0, stream>>>(src4, dst4, cursor, pairs,
                                                     (const float4*)x, (uint2*)xb, sums0,
                                                     W0, Ws, wtg);
    k_scan_bkt<<<1, 512, 0, stream>>>(cursor, bktBase, row_ptr);

    // ---- CSR finalize ----
    k_csr<<<NBKT, 256, 0, stream>>>(pairs, cursor, bktBase, row_ptr, dinv, col);

    // ---- gemm0 ----
    k_gemm0<<<GEMM_B, 256, 0, stream>>>(xb, wtg, sums0, bn0_g, bn0_b, b0, h0);

    // ---- layer 1 ----
    k_stats_h<<<400, 256, 0, stream>>>((const uint4*)h0, sums1);
    k_gemm_t<<<GT_B, 256, 0, stream>>>(h0, wt1, sums1, bns_g, bns_b, dinv, tbuf);
    k_agg<true><<<AGG_B, 256, 0, stream>>>((const uint2*)tbuf, row_ptr, col, dinv, bs, h1);

    // ---- layer 2 ----
    k_stats_h<<<400, 256, 0, stream>>>((const uint4*)h1, sums2);
    k_gemm_t<<<GT_B, 256, 0, stream>>>(h1, wt2, sums2, bns_g + HID, bns_b + HID, dinv, tbuf);
    k_agg<true><<<AGG_B, 256, 0, stream>>>((const uint2*)tbuf, row_ptr, col, dinv,
                                           bs + HID, h2);

    // ---- layer 3 (f32 out) ----
    k_stats_h<<<400, 256, 0, stream>>>((const uint4*)h2, sums3);
    k_gemm_t<<<GT_B, 256, 0, stream>>>(h2, wt3, sums3, bns_g + 2 * HID, bns_b + 2 * HID,
                                       dinv, tbuf);
    k_agg<false><<<AGG_B, 256, 0, stream>>>((const uint2*)tbuf, row_ptr, col, dinv,
                                            bs + 2 * HID, out);
}

// Round 20
// 218.632 us; speedup vs baseline: 1.1921x; 1.1921x over previous
//
#include <hip/hip_runtime.h>

#define N_NODES 100000
#define N_EDGES 1200000
#define IN_F 128
#define HID 64
#define BN_EPS 1e-5f
#define E4 (N_EDGES / 4)
#define NBKT 391       // ceil(100000/256) buckets; bucket = dst >> 8
#define BSLOT 4096     // slots per bucket region
#define NBB 293        // bucket-scatter blocks (4096 edges each, 512 threads)
#define SB 406         // stats_in virtual blocks (512 threads, 16 rows/round)
#define GEMM_B 1563    // ceil(100000/64)
#define GT_B 782       // ceil(100000/128) for 128-row gemm_t
#define AGG_B 12500    // 2 nodes/wave: 100000 / (4 waves * 2)

typedef unsigned int uint;
typedef unsigned short ushort;
typedef __attribute__((ext_vector_type(8))) short bf16x8;
typedef __attribute__((ext_vector_type(4))) float f32x4;

__device__ inline uint f2bf(float f) {        // f32 -> bf16 (RNE), low 16 bits
    uint u = __float_as_uint(f);
    return (u + 0x7fffu + ((u >> 16) & 1u)) >> 16;
}
__device__ inline float bflo(uint v) { return __uint_as_float(v << 16); }
__device__ inline float bfhi(uint v) { return __uint_as_float(v & 0xffff0000u); }

union U4B8 { uint4 u; bf16x8 b; };

// ---------------- K_B (512 thr): bucket scatter || stats(x)+xb || Wt prep ----------------
__global__ __launch_bounds__(512) void k_bucket_stats(
    const int4* __restrict__ src4, const int4* __restrict__ dst4,
    int* __restrict__ cursor, int* __restrict__ pairs,
    const float4* __restrict__ x4, uint2* __restrict__ xb2, float* __restrict__ sums,
    const float* __restrict__ W0, const float* __restrict__ Ws,
    ushort* __restrict__ wtg) {
    int t = threadIdx.x;
    if (blockIdx.x < NBB) {
        __shared__ int cnt_l[NBKT];
        __shared__ int base_l[NBKT];
        for (int i = t; i < NBKT; i += 512) cnt_l[i] = 0;
        __syncthreads();
        int4 d[2];
        int bk[8], rk[8];
#pragma unroll
        for (int k = 0; k < 2; k++) {
            int idx = blockIdx.x * 1024 + k * 512 + t;
            if (idx < E4) {
                int4 dv = dst4[idx];
                d[k] = dv;
                bk[k * 4 + 0] = dv.x >> 8;
                bk[k * 4 + 1] = dv.y >> 8;
                bk[k * 4 + 2] = dv.z >> 8;
                bk[k * 4 + 3] = dv.w >> 8;
                rk[k * 4 + 0] = atomicAdd(&cnt_l[bk[k * 4 + 0]], 1);
                rk[k * 4 + 1] = atomicAdd(&cnt_l[bk[k * 4 + 1]], 1);
                rk[k * 4 + 2] = atomicAdd(&cnt_l[bk[k * 4 + 2]], 1);
                rk[k * 4 + 3] = atomicAdd(&cnt_l[bk[k * 4 + 3]], 1);
            }
        }
        __syncthreads();
        for (int i = t; i < NBKT; i += 512) {
            int c = cnt_l[i];
            base_l[i] = c ? atomicAdd(&cursor[i], c) : 0;
        }
        __syncthreads();
#pragma unroll
        for (int k = 0; k < 2; k++) {
            int idx = blockIdx.x * 1024 + k * 512 + t;
            if (idx < E4) {
                int4 sv = src4[idx];
                int b0 = bk[k * 4 + 0], b1 = bk[k * 4 + 1];
                int b2 = bk[k * 4 + 2], b3 = bk[k * 4 + 3];
                pairs[b0 * BSLOT + base_l[b0] + rk[k * 4 + 0]] = sv.x | ((d[k].x & 255) << 24);
                pairs[b1 * BSLOT + base_l[b1] + rk[k * 4 + 1]] = sv.y | ((d[k].y & 255) << 24);
                pairs[b2 * BSLOT + base_l[b2] + rk[k * 4 + 2]] = sv.z | ((d[k].z & 255) << 24);
                pairs[b3 * BSLOT + base_l[b3] + rk[k * 4 + 3]] = sv.w | ((d[k].w & 255) << 24);
            }
        }
        return;
    }
    if (blockIdx.x >= NBB + SB) {
        // Wt prep, FRAGMENT-MAJOR: slot ((c*4+nt)*64 + lane)*8 + j holds
        // bf16(W[k= c*32+(lane>>4)*8+j][n= nt*16+(lane&15)]).
        for (int i = t; i < 8192; i += 512) {
            int j = i & 7, l = (i >> 3) & 63, f = i >> 9;
            int c = f >> 2, nt = f & 3, lr = l & 15, lg = l >> 4;
            int k = c * 32 + lg * 8 + j, n = nt * 16 + lr;
            wtg[i] = (ushort)f2bf(W0[k * 64 + n]);
        }
#pragma unroll
        for (int li = 0; li < 3; li++) {
            const float* Wl = Ws + li * 4096;
            ushort* wt = wtg + 8192 + li * 4096;
            for (int i = t; i < 4096; i += 512) {
                int j = i & 7, l = (i >> 3) & 63, f = i >> 9;  // f 0..7
                int c = f >> 2, nt = f & 3, lr = l & 15, lg = l >> 4;
                int k = c * 32 + lg * 8 + j, n = nt * 16 + lr;
                wt[i] = (ushort)f2bf(Wl[k * 64 + n]);
            }
        }
        return;
    }
    // ---- stats(x) + x->bf16 path (512 thr: 16 rows/round) ----
    __shared__ float lds[8][32][8];
    int vb = blockIdx.x - NBB;
    int cq = t & 31, rs = t >> 5;
    float s1[4] = {0.f, 0.f, 0.f, 0.f}, s2[4] = {0.f, 0.f, 0.f, 0.f};
    for (int row = vb * 16 + rs; row < N_NODES; row += SB * 16) {
        float4 v = x4[(size_t)row * 32 + cq];
        s1[0] += v.x; s2[0] += v.x * v.x;
        s1[1] += v.y; s2[1] += v.y * v.y;
        s1[2] += v.z; s2[2] += v.z * v.z;
        s1[3] += v.w; s2[3] += v.w * v.w;
        uint2 p;
        p.x = f2bf(v.x) | (f2bf(v.y) << 16);
        p.y = f2bf(v.z) | (f2bf(v.w) << 16);
        xb2[(size_t)row * 32 + cq] = p;
    }
#pragma unroll
    for (int j = 0; j < 4; j++) {
        s1[j] += __shfl_xor(s1[j], 32);
        s2[j] += __shfl_xor(s2[j], 32);
    }
    int w = t >> 6;
    if ((t & 63) < 32) {
#pragma unroll
        for (int j = 0; j < 4; j++) {
            lds[w][cq][j] = s1[j];
            lds[w][cq][4 + j] = s2[j];
        }
    }
    __syncthreads();
    if (t < 256) {
        int cq2 = t >> 3, k = t & 7;
        float v = 0.f;
#pragma unroll
        for (int ww = 0; ww < 8; ww++) v += lds[ww][cq2][k];
        int col = cq2 * 4 + (k & 3);
        atomicAdd(&sums[(k >> 2) * 128 + col], v);
    }
}

// ---------------- tiny scan over 391 bucket totals ----------------
__global__ __launch_bounds__(512) void k_scan_bkt(const int* __restrict__ cursor,
                                                  int* __restrict__ bucketBase,
                                                  int* __restrict__ row_ptr) {
    __shared__ int sb[512];
    int t = threadIdx.x;
    int v = (t < NBKT) ? cursor[t] : 0;
    sb[t] = v;
    __syncthreads();
    int x = v;
    for (int off = 1; off < 512; off <<= 1) {
        int y = (t >= off) ? sb[t - off] : 0;
        __syncthreads();
        x += y;
        sb[t] = x;
        __syncthreads();
    }
    if (t <= NBKT) bucketBase[t] = x - v;
    if (t == 0) row_ptr[N_NODES] = N_EDGES;
}

// ---------------- k_csr: per-bucket CSR finalize ----------------
__global__ __launch_bounds__(256) void k_csr(
    const int* __restrict__ pairs, const int* __restrict__ cursor,
    const int* __restrict__ bucketBase, int* __restrict__ row_ptr,
    float* __restrict__ dinv, int* __restrict__ col) {
    __shared__ int cnt_l[256];
    __shared__ int sb[256];
    __shared__ int sbex[256];
    int b = blockIdx.x;
    int t = threadIdx.x;
    int n = cursor[b];
    int base = bucketBase[b];
    const int* reg = pairs + (size_t)b * BSLOT;
    cnt_l[t] = 0;
    __syncthreads();
    int rk[16];
#pragma unroll
    for (int k = 0; k < 16; k++) {
        int e = k * 256 + t;
        if (e < n) {
            int p = reg[e];
            rk[k] = atomicAdd(&cnt_l[(uint)p >> 24], 1);
        }
    }
    __syncthreads();
    int c = cnt_l[t];
    sb[t] = c;
    __syncthreads();
    int x2 = c;
    for (int off = 1; off < 256; off <<= 1) {
        int y = (t >= off) ? sb[t - off] : 0;
        __syncthreads();
        x2 += y;
        sb[t] = x2;
        __syncthreads();
    }
    sbex[t] = x2 - c;
    int i = b * 256 + t;
    if (i < N_NODES) {
        dinv[i] = rsqrtf((float)(c + 1));
        row_ptr[i] = base + x2 - c;
    }
    __syncthreads();
#pragma unroll
    for (int k = 0; k < 16; k++) {
        int e = k * 256 + t;
        if (e < n) {
            int p = reg[e];
            col[base + sbex[(uint)p >> 24] + rk[k]] = p & 0xFFFFFF;
        }
    }
}

// ---------------- k_gemm0: BN(xb)@W0+bias, relu -> h0 bf16 ----------------
__global__ __launch_bounds__(256, 4) void k_gemm0(
    const ushort* __restrict__ xb, const ushort* __restrict__ wt0,
    const float* __restrict__ sums, const float* __restrict__ gamma,
    const float* __restrict__ beta, const float* __restrict__ bias,
    ushort* __restrict__ h0) {
    __shared__ float scale_s[IN_F], shift_s[IN_F];
    __shared__ ushort rep[4][1024];
    int t = threadIdx.x;
    int bid = blockIdx.x;
    if (t < IN_F) {
        float m = sums[t] * (1.0f / N_NODES);
        float var = sums[IN_F + t] * (1.0f / N_NODES) - m * m;
        float sc = gamma[t] * rsqrtf(var + BN_EPS);
        scale_s[t] = sc;
        shift_s[t] = beta[t] - m * sc;
    }
    __syncthreads();
    int w = t >> 6, l = t & 63, lr = l & 15, lg = l >> 4;
    int row = bid * 64 + w * 16 + lr;
    if (row >= N_NODES) row = N_NODES - 1;
    const ushort* xr = xb + (size_t)row * 128;
    uint4 av[4];
#pragma unroll
    for (int c = 0; c < 4; c++)
        av[c] = *(const uint4*)(xr + c * 32 + lg * 8);
    bf16x8 Bf[4][4];
#pragma unroll
    for (int c = 0; c < 4; c++)
#pragma unroll
        for (int nt = 0; nt < 4; nt++)
            Bf[c][nt] = *(const bf16x8*)(wt0 + ((c * 4 + nt) * 64 + l) * 8);
    bf16x8 af[4];
#pragma unroll
    for (int c = 0; c < 4; c++) {
        int k0 = c * 32 + lg * 8;
        float4 sc0 = *(const float4*)(scale_s + k0);
        float4 sc1 = *(const float4*)(scale_s + k0 + 4);
        float4 sh0 = *(const float4*)(shift_s + k0);
        float4 sh1 = *(const float4*)(shift_s + k0 + 4);
        U4B8 cvt;
        cvt.u.x = f2bf(bflo(av[c].x) * sc0.x + sh0.x) | (f2bf(bfhi(av[c].x) * sc0.y + sh0.y) << 16);
        cvt.u.y = f2bf(bflo(av[c].y) * sc0.z + sh0.z) | (f2bf(bfhi(av[c].y) * sc0.w + sh0.w) << 16);
        cvt.u.z = f2bf(bflo(av[c].z) * sc1.x + sh1.x) | (f2bf(bfhi(av[c].z) * sc1.y + sh1.y) << 16);
        cvt.u.w = f2bf(bflo(av[c].w) * sc1.z + sh1.z) | (f2bf(bfhi(av[c].w) * sc1.w + sh1.w) << 16);
        af[c] = cvt.b;
    }
    f32x4 acc[4];
#pragma unroll
    for (int nt = 0; nt < 4; nt++) acc[nt] = (f32x4){0.f, 0.f, 0.f, 0.f};
#pragma unroll
    for (int c = 0; c < 4; c++)
#pragma unroll
        for (int nt = 0; nt < 4; nt++)
            acc[nt] = __builtin_amdgcn_mfma_f32_16x16x32_bf16(af[c], Bf[c][nt], acc[nt], 0, 0, 0);

    int wrow0 = bid * 64 + w * 16;
    ushort* myA = rep[w];
    float bias_v[4];
#pragma unroll
    for (int nt = 0; nt < 4; nt++) bias_v[nt] = bias[nt * 16 + lr];
#pragma unroll
    for (int nt = 0; nt < 4; nt++) {
#pragma unroll
        for (int r = 0; r < 4; r++) {
            float v = fmaxf(acc[nt][r] + bias_v[nt], 0.f);
            int rowl = lg * 4 + r;
            int byte = (rowl * 128 + (nt * 16 + lr) * 2) ^ ((rowl & 7) << 4);
            *(ushort*)((char*)myA + byte) = (ushort)f2bf(v);
        }
    }
    {
        int rowl0 = l >> 3, kg0 = l & 7;
        int b0 = (rowl0 * 128 + kg0 * 16) ^ ((rowl0 & 7) << 4);
        int rowl1 = 8 + rowl0;
        int b1 = (rowl1 * 128 + kg0 * 16) ^ ((rowl1 & 7) << 4);
        uint4 v0 = *(uint4*)((char*)myA + b0);
        uint4 v1 = *(uint4*)((char*)myA + b1);
        size_t gg = (size_t)wrow0 * 128 + l * 16;
        if (wrow0 + rowl0 < N_NODES) *(uint4*)((char*)h0 + gg) = v0;
        if (wrow0 + rowl1 < N_NODES) *(uint4*)((char*)h0 + gg + 1024) = v1;
    }
}

// ---------------- k_gemm_t: 128 rows/block; t = (BN(h)@W)*dinv bf16 ----------------
__global__ __launch_bounds__(256, 4) void k_gemm_t(
    const ushort* __restrict__ h, const ushort* __restrict__ wt,
    const float* __restrict__ sums, const float* __restrict__ gamma,
    const float* __restrict__ beta, const float* __restrict__ dinv,
    ushort* __restrict__ out) {
    __shared__ float scale_s[HID], shift_s[HID];
    __shared__ ushort rep[4][1024];
    int t = threadIdx.x;
    if (t < HID) {
        float m = sums[t] * (1.0f / N_NODES);
        float var = sums[HID + t] * (1.0f / N_NODES) - m * m;
        float sc = gamma[t] * rsqrtf(var + BN_EPS);
        scale_s[t] = sc;
        shift_s[t] = beta[t] - m * sc;
    }
    __syncthreads();
    int w = t >> 6, l = t & 63, lr = l & 15, lg = l >> 4;
    int bid = blockIdx.x;
    int row0 = bid * 128 + w * 16 + lr;
    int row1 = row0 + 64;
    if (row0 >= N_NODES) row0 = N_NODES - 1;
    if (row1 >= N_NODES) row1 = N_NODES - 1;
    uint4 av0[2], av1[2];
#pragma unroll
    for (int c = 0; c < 2; c++) {
        av0[c] = *(const uint4*)(h + (size_t)row0 * 64 + c * 32 + lg * 8);
        av1[c] = *(const uint4*)(h + (size_t)row1 * 64 + c * 32 + lg * 8);
    }
    bf16x8 Bf[2][4];
#pragma unroll
    for (int c = 0; c < 2; c++)
#pragma unroll
        for (int nt = 0; nt < 4; nt++)
            Bf[c][nt] = *(const bf16x8*)(wt + ((c * 4 + nt) * 64 + l) * 8);
    bf16x8 af0[2], af1[2];
#pragma unroll
    for (int c = 0; c < 2; c++) {
        int k0 = c * 32 + lg * 8;
        float4 sc0 = *(const float4*)(scale_s + k0);
        float4 sc1 = *(const float4*)(scale_s + k0 + 4);
        float4 sh0 = *(const float4*)(shift_s + k0);
        float4 sh1 = *(const float4*)(shift_s + k0 + 4);
        U4B8 c0, c1;
        c0.u.x = f2bf(bflo(av0[c].x) * sc0.x + sh0.x) | (f2bf(bfhi(av0[c].x) * sc0.y + sh0.y) << 16);
        c0.u.y = f2bf(bflo(av0[c].y) * sc0.z + sh0.z) | (f2bf(bfhi(av0[c].y) * sc0.w + sh0.w) << 16);
        c0.u.z = f2bf(bflo(av0[c].z) * sc1.x + sh1.x) | (f2bf(bfhi(av0[c].z) * sc1.y + sh1.y) << 16);
        c0.u.w = f2bf(bflo(av0[c].w) * sc1.z + sh1.z) | (f2bf(bfhi(av0[c].w) * sc1.w + sh1.w) << 16);
        af0[c] = c0.b;
        c1.u.x = f2bf(bflo(av1[c].x) * sc0.x + sh0.x) | (f2bf(bfhi(av1[c].x) * sc0.y + sh0.y) << 16);
        c1.u.y = f2bf(bflo(av1[c].y) * sc0.z + sh0.z) | (f2bf(bfhi(av1[c].y) * sc0.w + sh0.w) << 16);
        c1.u.z = f2bf(bflo(av1[c].z) * sc1.x + sh1.x) | (f2bf(bfhi(av1[c].z) * sc1.y + sh1.y) << 16);
        c1.u.w = f2bf(bflo(av1[c].w) * sc1.z + sh1.z) | (f2bf(bfhi(av1[c].w) * sc1.w + sh1.w) << 16);
        af1[c] = c1.b;
    }
    f32x4 acc0[4], acc1[4];
#pragma unroll
    for (int nt = 0; nt < 4; nt++) {
        acc0[nt] = (f32x4){0.f, 0.f, 0.f, 0.f};
        acc1[nt] = (f32x4){0.f, 0.f, 0.f, 0.f};
    }
#pragma unroll
    for (int c = 0; c < 2; c++)
#pragma unroll
        for (int nt = 0; nt < 4; nt++) {
            acc0[nt] = __builtin_amdgcn_mfma_f32_16x16x32_bf16(af0[c], Bf[c][nt], acc0[nt], 0, 0, 0);
            acc1[nt] = __builtin_amdgcn_mfma_f32_16x16x32_bf16(af1[c], Bf[c][nt], acc1[nt], 0, 0, 0);
        }
    ushort* myA = rep[w];
#pragma unroll
    for (int s = 0; s < 2; s++) {
        int wrow0 = bid * 128 + s * 64 + w * 16;
        f32x4* acc = s ? acc1 : acc0;
        int dbase = wrow0 + lg * 4;
        if (dbase > N_NODES - 4) dbase = N_NODES - 4;
        float4 dv = *(const float4*)(dinv + dbase);
        float dvv[4] = {dv.x, dv.y, dv.z, dv.w};
#pragma unroll
        for (int nt = 0; nt < 4; nt++) {
#pragma unroll
            for (int r = 0; r < 4; r++) {
                float v = acc[nt][r] * dvv[r];
                int rowl = lg * 4 + r;
                int byte = (rowl * 128 + (nt * 16 + lr) * 2) ^ ((rowl & 7) << 4);
                *(ushort*)((char*)myA + byte) = (ushort)f2bf(v);
            }
        }
        int rowl0 = l >> 3, kg0 = l & 7;
        int b0 = (rowl0 * 128 + kg0 * 16) ^ ((rowl0 & 7) << 4);
        int rowl1 = 8 + rowl0;
        int b1 = (rowl1 * 128 + kg0 * 16) ^ ((rowl1 & 7) << 4);
        uint4 v0 = *(uint4*)((char*)myA + b0);
        uint4 v1 = *(uint4*)((char*)myA + b1);
        size_t gg = (size_t)wrow0 * 128 + l * 16;
        if (wrow0 + rowl0 < N_NODES) *(uint4*)((char*)out + gg) = v0;
        if (wrow0 + rowl1 < N_NODES) *(uint4*)((char*)out + gg + 1024) = v1;
    }
}

// ---------------- stats on bf16 h (C=64) ----------------
__global__ __launch_bounds__(256) void k_stats_h(const uint4* __restrict__ h4,
                                                 float* __restrict__ sums) {
    __shared__ float lds[4][8][16];
    int t = threadIdx.x;
    int cg = t & 7, rs = t >> 3;
    float s1[8], s2[8];
#pragma unroll
    for (int j = 0; j < 8; j++) { s1[j] = 0.f; s2[j] = 0.f; }
    for (int r = blockIdx.x * 32 + rs; r < N_NODES; r += gridDim.x * 32) {
        uint4 v = h4[(size_t)r * 8 + cg];
        float f;
        f = bflo(v.x); s1[0] += f; s2[0] += f * f;
        f = bfhi(v.x); s1[1] += f; s2[1] += f * f;
        f = bflo(v.y); s1[2] += f; s2[2] += f * f;
        f = bfhi(v.y); s1[3] += f; s2[3] += f * f;
        f = bflo(v.z); s1[4] += f; s2[4] += f * f;
        f = bfhi(v.z); s1[5] += f; s2[5] += f * f;
        f = bflo(v.w); s1[6] += f; s2[6] += f * f;
        f = bfhi(v.w); s1[7] += f; s2[7] += f * f;
    }
#pragma unroll
    for (int off = 8; off <= 32; off <<= 1) {
#pragma unroll
        for (int j = 0; j < 8; j++) {
            s1[j] += __shfl_xor(s1[j], off);
            s2[j] += __shfl_xor(s2[j], off);
        }
    }
    int w = t >> 6;
    if ((t & 63) < 8) {
#pragma unroll
        for (int j = 0; j < 8; j++) {
            lds[w][cg][j] = s1[j];
            lds[w][cg][8 + j] = s2[j];
        }
    }
    __syncthreads();
    if (t < 128) {
        int cg2 = t >> 4, k = t & 15;
        float v = lds[0][cg2][k] + lds[1][cg2][k] + lds[2][cg2][k] + lds[3][cg2][k];
        int col = cg2 * 8 + (k & 7);
        atomicAdd(&sums[(k >> 3) * 64 + col], v);
    }
}

// ---------------- per-node gather aggregation (2 nodes/wave, 2 groups x 16 x uint2) ----------------
template <bool OUT_BF16>
__global__ __launch_bounds__(256) void k_agg(const uint2* __restrict__ t2,
                                             const int* __restrict__ row_ptr,
                                             const int* __restrict__ col,
                                             const float* __restrict__ dinv,
                                             const float* __restrict__ bias,
                                             void* __restrict__ out) {
    int tid = threadIdx.x;
    int waveid = (blockIdx.x * 256 + tid) >> 6;
    int lane = tid & 63;
    int h = lane >> 5;        // node half (0/1)
    int hl = lane & 31;       // lane within half
    int g = hl >> 4;          // group within half (0/1)
    int q = hl & 15;          // elem within group (8B each)
    int wid = waveid * 2 + h; // N_NODES = 100000 even; AGG_B*8 == N_NODES exactly
    int e0 = row_ptr[wid], e1 = row_ptr[wid + 1];
    int deg = e1 - e0;
    int ce = e0 + hl;
    int cidx = col[(ce < e1) ? ce : 0];   // 32 edges per node, coalesced
    float a[4] = {0.f, 0.f, 0.f, 0.f};
    uint2 selfv = {0, 0};
    if (g == 0) selfv = t2[(size_t)wid * 16 + q];
    int degc = deg < 32 ? deg : 32;
    // 8 edges/iter per node, 4 gathers in flight per lane, 2 nodes per wave
    int hbase = h << 5;
    for (int d = 0; d < degc; d += 8) {
        int i0 = d + g, i1 = d + 2 + g, i2 = d + 4 + g, i3 = d + 6 + g;
        int s0 = __shfl(cidx, hbase | (i0 & 31));
        int s1 = __shfl(cidx, hbase | (i1 & 31));
        int s2 = __shfl(cidx, hbase | (i2 & 31));
        int s3 = __shfl(cidx, hbase | (i3 & 31));
        bool k0 = i0 < degc, k1 = i1 < degc, k2 = i2 < degc, k3 = i3 < degc;
        uint2 v0 = t2[(size_t)(k0 ? s0 : wid) * 16 + q];
        uint2 v1 = t2[(size_t)(k1 ? s1 : wid) * 16 + q];
        uint2 v2 = t2[(size_t)(k2 ? s2 : wid) * 16 + q];
        uint2 v3 = t2[(size_t)(k3 ? s3 : wid) * 16 + q];
        if (k0) {
            a[0] += bflo(v0.x); a[1] += bfhi(v0.x);
            a[2] += bflo(v0.y); a[3] += bfhi(v0.y);
        }
        if (k1) {
            a[0] += bflo(v1.x); a[1] += bfhi(v1.x);
            a[2] += bflo(v1.y); a[3] += bfhi(v1.y);
        }
        if (k2) {
            a[0] += bflo(v2.x); a[1] += bfhi(v2.x);
            a[2] += bflo(v2.y); a[3] += bfhi(v2.y);
        }
        if (k3) {
            a[0] += bflo(v3.x); a[1] += bfhi(v3.x);
            a[2] += bflo(v3.y); a[3] += bfhi(v3.y);
        }
    }
    for (int base = e0 + 32; base < e1; base += 2) {   // deg>32 tail (rare)
        int ee = base + g;
        if (ee < e1) {
            int s = col[ee];
            uint2 v = t2[(size_t)s * 16 + q];
            a[0] += bflo(v.x); a[1] += bfhi(v.x);
            a[2] += bflo(v.y); a[3] += bfhi(v.y);
        }
    }
    if (g == 0) {
        a[0] += bflo(selfv.x); a[1] += bfhi(selfv.x);
        a[2] += bflo(selfv.y); a[3] += bfhi(selfv.y);
    }
    // fold 2 groups within each half (xor 16 stays inside the 32-lane half)
#pragma unroll
    for (int j = 0; j < 4; j++) a[j] += __shfl_xor(a[j], 16);
    if (g == 0) {
        float di = dinv[wid];
        float4 b4 = reinterpret_cast<const float4*>(bias)[q];
        float r0 = fmaxf(di * a[0] + b4.x, 0.f);
        float r1 = fmaxf(di * a[1] + b4.y, 0.f);
        float r2 = fmaxf(di * a[2] + b4.z, 0.f);
        float r3 = fmaxf(di * a[3] + b4.w, 0.f);
        if (OUT_BF16) {
            uint2 o;
            o.x = f2bf(r0) | (f2bf(r1) << 16);
            o.y = f2bf(r2) | (f2bf(r3) << 16);
            ((uint2*)out)[(size_t)wid * 16 + q] = o;
        } else {
            ((float4*)out)[(size_t)wid * 16 + q] = (float4){r0, r1, r2, r3};
        }
    }
}

// ---------------- launch ----------------

extern "C" void kernel_launch(void* const* d_in, const int* in_sizes, int n_in,
                              void* d_out, int out_size, void* d_ws, size_t ws_size,
                              hipStream_t stream) {
    const float* x = (const float*)d_in[0];
    const int* ei = (const int*)d_in[1];
    const int4* src4 = (const int4*)ei;
    const int4* dst4 = (const int4*)(ei + N_EDGES);
    const float* bn0_g = (const float*)d_in[2];
    const float* bn0_b = (const float*)d_in[3];
    const float* W0 = (const float*)d_in[4];
    const float* b0 = (const float*)d_in[5];
    const float* bns_g = (const float*)d_in[6];
    const float* bns_b = (const float*)d_in[7];
    const float* Ws = (const float*)d_in[8];
    const float* bs = (const float*)d_in[9];
    float* out = (float*)d_out;
    char* ws = (char*)d_ws;

    // workspace layout (bytes); xb dead after k_gemm0 -> h1 and tbuf alias its halves
    float*  dinv    = (float*)(ws + 0);          //   400,128
    int*    row_ptr = (int*)(ws + 400128);       //   400,384
    int*    col     = (int*)(ws + 800512);       // 4,800,000
    int*    cursor  = (int*)(ws + 5600512);      //     1,600
    float*  sums    = (float*)(ws + 5602112);    //     2,560
    int*    bktBase = (int*)(ws + 5604672);      //     1,600
    ushort* wtg     = (ushort*)(ws + 5606272);   //    40,960
    int*    pairs   = (int*)(ws + 5647232);      //  6,406,144
    ushort* h0      = (ushort*)(ws + 12053376);  // 12,800,000
    ushort* xb      = (ushort*)(ws + 24853376);  // 25,600,000
    ushort* h1      = (ushort*)(ws + 24853376);  // 12,800,000 (aliases xb lower half)
    ushort* tbuf    = (ushort*)(ws + 37653376);  // 12,800,000 (aliases xb upper half) -> 50.5MB
    ushort* h2      = h0;                        // h0 dead after gemm_t1
    float* sums0 = sums;          // 256 floats (IN_F)
    float* sums1 = sums + 256;    // 128
    float* sums2 = sums + 384;    // 128
    float* sums3 = sums + 512;    // 128
    const ushort* wt1 = wtg + 8192;
    const ushort* wt2 = wtg + 8192 + 4096;
    const ushort* wt3 = wtg + 8192 + 8192;

    hipMemsetAsync(cursor, 0, 1600 + 640 * sizeof(float), stream);

    // ---- K_B (512 thr): bucket scatter || stats(x)+xb || Wt prep ----
    k_bucket_stats<<<NBB + SB + 1, 512, 0, stream>>>(src4, dst4, cursor, pairs,
                                                     (const float4*)x, (uint2*)xb, sums0,
                                                     W0, Ws, wtg);
    k_scan_bkt<<<1, 512, 0, stream>>>(cursor, bktBase, row_ptr);

    // ---- CSR finalize ----
    k_csr<<<NBKT, 256, 0, stream>>>(pairs, cursor, bktBase, row_ptr, dinv, col);

    // ---- gemm0 ----
    k_gemm0<<<GEMM_B, 256, 0, stream>>>(xb, wtg, sums0, bn0_g, bn0_b, b0, h0);

    // ---- layer 1 ----
    k_stats_h<<<400, 256, 0, stream>>>((const uint4*)h0, sums1);
    k_gemm_t<<<GT_B, 256, 0, stream>>>(h0, wt1, sums1, bns_g, bns_b, dinv, tbuf);
    k_agg<true><<<AGG_B, 256, 0, stream>>>((const uint2*)tbuf, row_ptr, col, dinv, bs, h1);

    // ---- layer 2 ----
    k_stats_h<<<400, 256, 0, stream>>>((const uint4*)h1, sums2);
    k_gemm_t<<<GT_B, 256, 0, stream>>>(h1, wt2, sums2, bns_g + HID, bns_b + HID, dinv, tbuf);
    k_agg<true><<<AGG_B, 256, 0, stream>>>((const uint2*)tbuf, row_ptr, col, dinv,
                                           bs + HID, h2);

    // ---- layer 3 (f32 out) ----
    k_stats_h<<<400, 256, 0, stream>>>((const uint4*)h2, sums3);
    k_gemm_t<<<GT_B, 256, 0, stream>>>(h2, wt3, sums3, bns_g + 2 * HID, bns_b + 2 * HID,
                                       dinv, tbuf);
    k_agg<false><<<AGG_B, 256, 0, stream>>>((const uint2*)tbuf, row_ptr, col, dinv,
                                            bs + 2 * HID, out);
}

// Round 21
// 207.935 us; speedup vs baseline: 1.2534x; 1.0514x over previous
//
#include <hip/hip_runtime.h>

#define N_NODES 100000
#define N_EDGES 1200000
#define IN_F 128
#define HID 64
#define BN_EPS 1e-5f
#define E4 (N_EDGES / 4)
#define NBKT 391       // ceil(100000/256) buckets; bucket = dst >> 8
#define BSLOT 4096     // slots per bucket region
#define NBB 293        // bucket-scatter blocks (4096 edges each, 512 threads)
#define SB 406         // stats_in virtual blocks (512 threads, 16 rows/round)
#define GEMM_B 1563    // ceil(100000/64)
#define GT_B 782       // ceil(100000/128) for 128-row gemm_t
#define AGG_B 12500    // 2 nodes/wave: 100000 / (4 waves * 2)

typedef unsigned int uint;
typedef unsigned short ushort;
typedef __attribute__((ext_vector_type(8))) short bf16x8;
typedef __attribute__((ext_vector_type(4))) float f32x4;

__device__ inline uint f2bf(float f) {        // f32 -> bf16 (RNE), low 16 bits
    uint u = __float_as_uint(f);
    return (u + 0x7fffu + ((u >> 16) & 1u)) >> 16;
}
__device__ inline float bflo(uint v) { return __uint_as_float(v << 16); }
__device__ inline float bfhi(uint v) { return __uint_as_float(v & 0xffff0000u); }

union U4B8 { uint4 u; bf16x8 b; };

// ---------------- K_B (512 thr): bucket scatter || stats(x)+xb || Wt prep ----------------
__global__ __launch_bounds__(512) void k_bucket_stats(
    const int4* __restrict__ src4, const int4* __restrict__ dst4,
    int* __restrict__ cursor, int* __restrict__ pairs,
    const float4* __restrict__ x4, uint2* __restrict__ xb2, float* __restrict__ sums,
    const float* __restrict__ W0, const float* __restrict__ Ws,
    ushort* __restrict__ wtg) {
    int t = threadIdx.x;
    if (blockIdx.x < NBB) {
        __shared__ int cnt_l[NBKT];
        __shared__ int base_l[NBKT];
        for (int i = t; i < NBKT; i += 512) cnt_l[i] = 0;
        __syncthreads();
        int i0 = blockIdx.x * 1024 + t;
        int i1 = i0 + 512;
        bool v0 = i0 < E4, v1 = i1 < E4;
        int4 d0, d1;
        if (v0) d0 = dst4[i0];            // both loads issued before atomics
        if (v1) d1 = dst4[i1];
        int bk[8], rk[8];
        if (v0) {
            bk[0] = d0.x >> 8; bk[1] = d0.y >> 8; bk[2] = d0.z >> 8; bk[3] = d0.w >> 8;
            rk[0] = atomicAdd(&cnt_l[bk[0]], 1);
            rk[1] = atomicAdd(&cnt_l[bk[1]], 1);
            rk[2] = atomicAdd(&cnt_l[bk[2]], 1);
            rk[3] = atomicAdd(&cnt_l[bk[3]], 1);
        }
        if (v1) {
            bk[4] = d1.x >> 8; bk[5] = d1.y >> 8; bk[6] = d1.z >> 8; bk[7] = d1.w >> 8;
            rk[4] = atomicAdd(&cnt_l[bk[4]], 1);
            rk[5] = atomicAdd(&cnt_l[bk[5]], 1);
            rk[6] = atomicAdd(&cnt_l[bk[6]], 1);
            rk[7] = atomicAdd(&cnt_l[bk[7]], 1);
        }
        __syncthreads();
        for (int i = t; i < NBKT; i += 512) {
            int c = cnt_l[i];
            base_l[i] = c ? atomicAdd(&cursor[i], c) : 0;
        }
        __syncthreads();
        if (v0) {
            int4 sv = src4[i0];
            pairs[bk[0] * BSLOT + base_l[bk[0]] + rk[0]] = sv.x | ((d0.x & 255) << 24);
            pairs[bk[1] * BSLOT + base_l[bk[1]] + rk[1]] = sv.y | ((d0.y & 255) << 24);
            pairs[bk[2] * BSLOT + base_l[bk[2]] + rk[2]] = sv.z | ((d0.z & 255) << 24);
            pairs[bk[3] * BSLOT + base_l[bk[3]] + rk[3]] = sv.w | ((d0.w & 255) << 24);
        }
        if (v1) {
            int4 sv = src4[i1];
            pairs[bk[4] * BSLOT + base_l[bk[4]] + rk[4]] = sv.x | ((d1.x & 255) << 24);
            pairs[bk[5] * BSLOT + base_l[bk[5]] + rk[5]] = sv.y | ((d1.y & 255) << 24);
            pairs[bk[6] * BSLOT + base_l[bk[6]] + rk[6]] = sv.z | ((d1.z & 255) << 24);
            pairs[bk[7] * BSLOT + base_l[bk[7]] + rk[7]] = sv.w | ((d1.w & 255) << 24);
        }
        return;
    }
    if (blockIdx.x >= NBB + SB) {
        // Wt prep, FRAGMENT-MAJOR: slot ((c*4+nt)*64 + lane)*8 + j holds
        // bf16(W[k= c*32+(lane>>4)*8+j][n= nt*16+(lane&15)]).
        for (int i = t; i < 8192; i += 512) {
            int j = i & 7, l = (i >> 3) & 63, f = i >> 9;
            int c = f >> 2, nt = f & 3, lr = l & 15, lg = l >> 4;
            int k = c * 32 + lg * 8 + j, n = nt * 16 + lr;
            wtg[i] = (ushort)f2bf(W0[k * 64 + n]);
        }
#pragma unroll
        for (int li = 0; li < 3; li++) {
            const float* Wl = Ws + li * 4096;
            ushort* wt = wtg + 8192 + li * 4096;
            for (int i = t; i < 4096; i += 512) {
                int j = i & 7, l = (i >> 3) & 63, f = i >> 9;  // f 0..7
                int c = f >> 2, nt = f & 3, lr = l & 15, lg = l >> 4;
                int k = c * 32 + lg * 8 + j, n = nt * 16 + lr;
                wt[i] = (ushort)f2bf(Wl[k * 64 + n]);
            }
        }
        return;
    }
    // ---- stats(x) + x->bf16 path (512 thr: 16 rows/round) ----
    __shared__ float lds[8][32][8];
    int vb = blockIdx.x - NBB;
    int cq = t & 31, rs = t >> 5;
    float s1[4] = {0.f, 0.f, 0.f, 0.f}, s2[4] = {0.f, 0.f, 0.f, 0.f};
    for (int row = vb * 16 + rs; row < N_NODES; row += SB * 16) {
        float4 v = x4[(size_t)row * 32 + cq];
        s1[0] += v.x; s2[0] += v.x * v.x;
        s1[1] += v.y; s2[1] += v.y * v.y;
        s1[2] += v.z; s2[2] += v.z * v.z;
        s1[3] += v.w; s2[3] += v.w * v.w;
        uint2 p;
        p.x = f2bf(v.x) | (f2bf(v.y) << 16);
        p.y = f2bf(v.z) | (f2bf(v.w) << 16);
        xb2[(size_t)row * 32 + cq] = p;
    }
#pragma unroll
    for (int j = 0; j < 4; j++) {
        s1[j] += __shfl_xor(s1[j], 32);
        s2[j] += __shfl_xor(s2[j], 32);
    }
    int w = t >> 6;
    if ((t & 63) < 32) {
#pragma unroll
        for (int j = 0; j < 4; j++) {
            lds[w][cq][j] = s1[j];
            lds[w][cq][4 + j] = s2[j];
        }
    }
    __syncthreads();
    if (t < 256) {
        int cq2 = t >> 3, k = t & 7;
        float v = 0.f;
#pragma unroll
        for (int ww = 0; ww < 8; ww++) v += lds[ww][cq2][k];
        int col = cq2 * 4 + (k & 3);
        atomicAdd(&sums[(k >> 2) * 128 + col], v);
    }
}

// ---------------- tiny scan over 391 bucket totals ----------------
__global__ __launch_bounds__(512) void k_scan_bkt(const int* __restrict__ cursor,
                                                  int* __restrict__ bucketBase,
                                                  int* __restrict__ row_ptr) {
    __shared__ int sb[512];
    int t = threadIdx.x;
    int v = (t < NBKT) ? cursor[t] : 0;
    sb[t] = v;
    __syncthreads();
    int x = v;
    for (int off = 1; off < 512; off <<= 1) {
        int y = (t >= off) ? sb[t - off] : 0;
        __syncthreads();
        x += y;
        sb[t] = x;
        __syncthreads();
    }
    if (t <= NBKT) bucketBase[t] = x - v;
    if (t == 0) row_ptr[N_NODES] = N_EDGES;
}

// ---------------- fused: per-bucket CSR finalize || gemm0 ----------------
__global__ __launch_bounds__(256, 4) void k_csr_gemm0(
    const int* __restrict__ pairs, const int* __restrict__ cursor,
    const int* __restrict__ bucketBase, int* __restrict__ row_ptr,
    float* __restrict__ dinv, int* __restrict__ col,
    const ushort* __restrict__ xb, const ushort* __restrict__ wt0,
    const float* __restrict__ sums, const float* __restrict__ gamma,
    const float* __restrict__ beta, const float* __restrict__ bias,
    ushort* __restrict__ h0) {
    __shared__ int csr_a[256], csr_b[256], csr_c[256];
    __shared__ float scale_s[IN_F], shift_s[IN_F];
    __shared__ ushort rep[4][1024];
    int t = threadIdx.x;
    if (blockIdx.x < NBKT) {
        int* cnt_l = csr_a;
        int* sb = csr_b;
        int* sbex = csr_c;
        int b = blockIdx.x;
        int n = cursor[b];
        int base = bucketBase[b];
        const int* reg = pairs + (size_t)b * BSLOT;
        cnt_l[t] = 0;
        __syncthreads();
        int rk[16];
#pragma unroll
        for (int k = 0; k < 16; k++) {
            int e = k * 256 + t;
            if (e < n) {
                int p = reg[e];
                rk[k] = atomicAdd(&cnt_l[(uint)p >> 24], 1);
            }
        }
        __syncthreads();
        int c = cnt_l[t];
        sb[t] = c;
        __syncthreads();
        int x2 = c;
        for (int off = 1; off < 256; off <<= 1) {
            int y = (t >= off) ? sb[t - off] : 0;
            __syncthreads();
            x2 += y;
            sb[t] = x2;
            __syncthreads();
        }
        sbex[t] = x2 - c;
        int i = b * 256 + t;
        if (i < N_NODES) {
            dinv[i] = rsqrtf((float)(c + 1));
            row_ptr[i] = base + x2 - c;
        }
        __syncthreads();
#pragma unroll
        for (int k = 0; k < 16; k++) {
            int e = k * 256 + t;
            if (e < n) {
                int p = reg[e];
                col[base + sbex[(uint)p >> 24] + rk[k]] = p & 0xFFFFFF;
            }
        }
        return;
    }
    // ---- gemm0 path ----
    int bid = blockIdx.x - NBKT;
    if (t < IN_F) {
        float m = sums[t] * (1.0f / N_NODES);
        float var = sums[IN_F + t] * (1.0f / N_NODES) - m * m;
        float sc = gamma[t] * rsqrtf(var + BN_EPS);
        scale_s[t] = sc;
        shift_s[t] = beta[t] - m * sc;
    }
    __syncthreads();
    int w = t >> 6, l = t & 63, lr = l & 15, lg = l >> 4;
    int row = bid * 64 + w * 16 + lr;
    if (row >= N_NODES) row = N_NODES - 1;
    const ushort* xr = xb + (size_t)row * 128;
    uint4 av[4];
#pragma unroll
    for (int c = 0; c < 4; c++)
        av[c] = *(const uint4*)(xr + c * 32 + lg * 8);
    bf16x8 Bf[4][4];
#pragma unroll
    for (int c = 0; c < 4; c++)
#pragma unroll
        for (int nt = 0; nt < 4; nt++)
            Bf[c][nt] = *(const bf16x8*)(wt0 + ((c * 4 + nt) * 64 + l) * 8);
    bf16x8 af[4];
#pragma unroll
    for (int c = 0; c < 4; c++) {
        int k0 = c * 32 + lg * 8;
        float4 sc0 = *(const float4*)(scale_s + k0);
        float4 sc1 = *(const float4*)(scale_s + k0 + 4);
        float4 sh0 = *(const float4*)(shift_s + k0);
        float4 sh1 = *(const float4*)(shift_s + k0 + 4);
        U4B8 cvt;
        cvt.u.x = f2bf(bflo(av[c].x) * sc0.x + sh0.x) | (f2bf(bfhi(av[c].x) * sc0.y + sh0.y) << 16);
        cvt.u.y = f2bf(bflo(av[c].y) * sc0.z + sh0.z) | (f2bf(bfhi(av[c].y) * sc0.w + sh0.w) << 16);
        cvt.u.z = f2bf(bflo(av[c].z) * sc1.x + sh1.x) | (f2bf(bfhi(av[c].z) * sc1.y + sh1.y) << 16);
        cvt.u.w = f2bf(bflo(av[c].w) * sc1.z + sh1.z) | (f2bf(bfhi(av[c].w) * sc1.w + sh1.w) << 16);
        af[c] = cvt.b;
    }
    f32x4 acc[4];
#pragma unroll
    for (int nt = 0; nt < 4; nt++) acc[nt] = (f32x4){0.f, 0.f, 0.f, 0.f};
#pragma unroll
    for (int c = 0; c < 4; c++)
#pragma unroll
        for (int nt = 0; nt < 4; nt++)
            acc[nt] = __builtin_amdgcn_mfma_f32_16x16x32_bf16(af[c], Bf[c][nt], acc[nt], 0, 0, 0);

    int wrow0 = bid * 64 + w * 16;
    ushort* myA = rep[w];
    float bias_v[4];
#pragma unroll
    for (int nt = 0; nt < 4; nt++) bias_v[nt] = bias[nt * 16 + lr];
#pragma unroll
    for (int nt = 0; nt < 4; nt++) {
#pragma unroll
        for (int r = 0; r < 4; r++) {
            float v = fmaxf(acc[nt][r] + bias_v[nt], 0.f);
            int rowl = lg * 4 + r;
            int byte = (rowl * 128 + (nt * 16 + lr) * 2) ^ ((rowl & 7) << 4);
            *(ushort*)((char*)myA + byte) = (ushort)f2bf(v);
        }
    }
    {
        int rowl0 = l >> 3, kg0 = l & 7;
        int b0 = (rowl0 * 128 + kg0 * 16) ^ ((rowl0 & 7) << 4);
        int rowl1 = 8 + rowl0;
        int b1 = (rowl1 * 128 + kg0 * 16) ^ ((rowl1 & 7) << 4);
        uint4 v0 = *(uint4*)((char*)myA + b0);
        uint4 v1 = *(uint4*)((char*)myA + b1);
        size_t gg = (size_t)wrow0 * 128 + l * 16;
        if (wrow0 + rowl0 < N_NODES) *(uint4*)((char*)h0 + gg) = v0;
        if (wrow0 + rowl1 < N_NODES) *(uint4*)((char*)h0 + gg + 1024) = v1;
    }
}

// ---------------- k_gemm_t: 128 rows/block; t = (BN(h)@W)*dinv bf16 ----------------
__global__ __launch_bounds__(256, 4) void k_gemm_t(
    const ushort* __restrict__ h, const ushort* __restrict__ wt,
    const float* __restrict__ sums, const float* __restrict__ gamma,
    const float* __restrict__ beta, const float* __restrict__ dinv,
    ushort* __restrict__ out) {
    __shared__ float scale_s[HID], shift_s[HID];
    __shared__ ushort rep[4][1024];
    int t = threadIdx.x;
    if (t < HID) {
        float m = sums[t] * (1.0f / N_NODES);
        float var = sums[HID + t] * (1.0f / N_NODES) - m * m;
        float sc = gamma[t] * rsqrtf(var + BN_EPS);
        scale_s[t] = sc;
        shift_s[t] = beta[t] - m * sc;
    }
    __syncthreads();
    int w = t >> 6, l = t & 63, lr = l & 15, lg = l >> 4;
    int bid = blockIdx.x;
    int row0 = bid * 128 + w * 16 + lr;
    int row1 = row0 + 64;
    if (row0 >= N_NODES) row0 = N_NODES - 1;
    if (row1 >= N_NODES) row1 = N_NODES - 1;
    uint4 av0[2], av1[2];
#pragma unroll
    for (int c = 0; c < 2; c++) {
        av0[c] = *(const uint4*)(h + (size_t)row0 * 64 + c * 32 + lg * 8);
        av1[c] = *(const uint4*)(h + (size_t)row1 * 64 + c * 32 + lg * 8);
    }
    bf16x8 Bf[2][4];
#pragma unroll
    for (int c = 0; c < 2; c++)
#pragma unroll
        for (int nt = 0; nt < 4; nt++)
            Bf[c][nt] = *(const bf16x8*)(wt + ((c * 4 + nt) * 64 + l) * 8);
    bf16x8 af0[2], af1[2];
#pragma unroll
    for (int c = 0; c < 2; c++) {
        int k0 = c * 32 + lg * 8;
        float4 sc0 = *(const float4*)(scale_s + k0);
        float4 sc1 = *(const float4*)(scale_s + k0 + 4);
        float4 sh0 = *(const float4*)(shift_s + k0);
        float4 sh1 = *(const float4*)(shift_s + k0 + 4);
        U4B8 c0, c1;
        c0.u.x = f2bf(bflo(av0[c].x) * sc0.x + sh0.x) | (f2bf(bfhi(av0[c].x) * sc0.y + sh0.y) << 16);
        c0.u.y = f2bf(bflo(av0[c].y) * sc0.z + sh0.z) | (f2bf(bfhi(av0[c].y) * sc0.w + sh0.w) << 16);
        c0.u.z = f2bf(bflo(av0[c].z) * sc1.x + sh1.x) | (f2bf(bfhi(av0[c].z) * sc1.y + sh1.y) << 16);
        c0.u.w = f2bf(bflo(av0[c].w) * sc1.z + sh1.z) | (f2bf(bfhi(av0[c].w) * sc1.w + sh1.w) << 16);
        af0[c] = c0.b;
        c1.u.x = f2bf(bflo(av1[c].x) * sc0.x + sh0.x) | (f2bf(bfhi(av1[c].x) * sc0.y + sh0.y) << 16);
        c1.u.y = f2bf(bflo(av1[c].y) * sc0.z + sh0.z) | (f2bf(bfhi(av1[c].y) * sc0.w + sh0.w) << 16);
        c1.u.z = f2bf(bflo(av1[c].z) * sc1.x + sh1.x) | (f2bf(bfhi(av1[c].z) * sc1.y + sh1.y) << 16);
        c1.u.w = f2bf(bflo(av1[c].w) * sc1.z + sh1.z) | (f2bf(bfhi(av1[c].w) * sc1.w + sh1.w) << 16);
        af1[c] = c1.b;
    }
    f32x4 acc0[4], acc1[4];
#pragma unroll
    for (int nt = 0; nt < 4; nt++) {
        acc0[nt] = (f32x4){0.f, 0.f, 0.f, 0.f};
        acc1[nt] = (f32x4){0.f, 0.f, 0.f, 0.f};
    }
#pragma unroll
    for (int c = 0; c < 2; c++)
#pragma unroll
        for (int nt = 0; nt < 4; nt++) {
            acc0[nt] = __builtin_amdgcn_mfma_f32_16x16x32_bf16(af0[c], Bf[c][nt], acc0[nt], 0, 0, 0);
            acc1[nt] = __builtin_amdgcn_mfma_f32_16x16x32_bf16(af1[c], Bf[c][nt], acc1[nt], 0, 0, 0);
        }
    ushort* myA = rep[w];
#pragma unroll
    for (int s = 0; s < 2; s++) {
        int wrow0 = bid * 128 + s * 64 + w * 16;
        f32x4* acc = s ? acc1 : acc0;
        int dbase = wrow0 + lg * 4;
        if (dbase > N_NODES - 4) dbase = N_NODES - 4;
        float4 dv = *(const float4*)(dinv + dbase);
        float dvv[4] = {dv.x, dv.y, dv.z, dv.w};
#pragma unroll
        for (int nt = 0; nt < 4; nt++) {
#pragma unroll
            for (int r = 0; r < 4; r++) {
                float v = acc[nt][r] * dvv[r];
                int rowl = lg * 4 + r;
                int byte = (rowl * 128 + (nt * 16 + lr) * 2) ^ ((rowl & 7) << 4);
                *(ushort*)((char*)myA + byte) = (ushort)f2bf(v);
            }
        }
        int rowl0 = l >> 3, kg0 = l & 7;
        int b0 = (rowl0 * 128 + kg0 * 16) ^ ((rowl0 & 7) << 4);
        int rowl1 = 8 + rowl0;
        int b1 = (rowl1 * 128 + kg0 * 16) ^ ((rowl1 & 7) << 4);
        uint4 v0 = *(uint4*)((char*)myA + b0);
        uint4 v1 = *(uint4*)((char*)myA + b1);
        size_t gg = (size_t)wrow0 * 128 + l * 16;
        if (wrow0 + rowl0 < N_NODES) *(uint4*)((char*)out + gg) = v0;
        if (wrow0 + rowl1 < N_NODES) *(uint4*)((char*)out + gg + 1024) = v1;
    }
}

// ---------------- stats on bf16 h (C=64) ----------------
__global__ __launch_bounds__(256) void k_stats_h(const uint4* __restrict__ h4,
                                                 float* __restrict__ sums) {
    __shared__ float lds[4][8][16];
    int t = threadIdx.x;
    int cg = t & 7, rs = t >> 3;
    float s1[8], s2[8];
#pragma unroll
    for (int j = 0; j < 8; j++) { s1[j] = 0.f; s2[j] = 0.f; }
    for (int r = blockIdx.x * 32 + rs; r < N_NODES; r += gridDim.x * 32) {
        uint4 v = h4[(size_t)r * 8 + cg];
        float f;
        f = bflo(v.x); s1[0] += f; s2[0] += f * f;
        f = bfhi(v.x); s1[1] += f; s2[1] += f * f;
        f = bflo(v.y); s1[2] += f; s2[2] += f * f;
        f = bfhi(v.y); s1[3] += f; s2[3] += f * f;
        f = bflo(v.z); s1[4] += f; s2[4] += f * f;
        f = bfhi(v.z); s1[5] += f; s2[5] += f * f;
        f = bflo(v.w); s1[6] += f; s2[6] += f * f;
        f = bfhi(v.w); s1[7] += f; s2[7] += f * f;
    }
#pragma unroll
    for (int off = 8; off <= 32; off <<= 1) {
#pragma unroll
        for (int j = 0; j < 8; j++) {
            s1[j] += __shfl_xor(s1[j], off);
            s2[j] += __shfl_xor(s2[j], off);
        }
    }
    int w = t >> 6;
    if ((t & 63) < 8) {
#pragma unroll
        for (int j = 0; j < 8; j++) {
            lds[w][cg][j] = s1[j];
            lds[w][cg][8 + j] = s2[j];
        }
    }
    __syncthreads();
    if (t < 128) {
        int cg2 = t >> 4, k = t & 15;
        float v = lds[0][cg2][k] + lds[1][cg2][k] + lds[2][cg2][k] + lds[3][cg2][k];
        int col = cg2 * 8 + (k & 7);
        atomicAdd(&sums[(k >> 3) * 64 + col], v);
    }
}

// ---------------- per-node gather aggregation (2 nodes/wave, 2 groups x 16 x uint2) ----------------
template <bool OUT_BF16>
__global__ __launch_bounds__(256) void k_agg(const uint2* __restrict__ t2,
                                             const int* __restrict__ row_ptr,
                                             const int* __restrict__ col,
                                             const float* __restrict__ dinv,
                                             const float* __restrict__ bias,
                                             void* __restrict__ out) {
    int tid = threadIdx.x;
    int waveid = (blockIdx.x * 256 + tid) >> 6;
    int lane = tid & 63;
    int h = lane >> 5;        // node half (0/1)
    int hl = lane & 31;       // lane within half
    int g = hl >> 4;          // group within half (0/1)
    int q = hl & 15;          // elem within group (8B each)
    int wid = waveid * 2 + h; // N_NODES even; AGG_B*8 == N_NODES exactly
    int e0 = row_ptr[wid], e1 = row_ptr[wid + 1];
    int deg = e1 - e0;
    int ce = e0 + hl;
    int cidx = col[(ce < e1) ? ce : 0];   // 32 edges per node, coalesced
    float a[4] = {0.f, 0.f, 0.f, 0.f};
    uint2 selfv = {0, 0};
    if (g == 0) selfv = t2[(size_t)wid * 16 + q];
    int degc = deg < 32 ? deg : 32;
    int hbase = h << 5;
    for (int d = 0; d < degc; d += 8) {
        int i0 = d + g, i1 = d + 2 + g, i2 = d + 4 + g, i3 = d + 6 + g;
        int s0 = __shfl(cidx, hbase | (i0 & 31));
        int s1 = __shfl(cidx, hbase | (i1 & 31));
        int s2 = __shfl(cidx, hbase | (i2 & 31));
        int s3 = __shfl(cidx, hbase | (i3 & 31));
        bool k0 = i0 < degc, k1 = i1 < degc, k2 = i2 < degc, k3 = i3 < degc;
        uint2 v0 = t2[(size_t)(k0 ? s0 : wid) * 16 + q];
        uint2 v1 = t2[(size_t)(k1 ? s1 : wid) * 16 + q];
        uint2 v2 = t2[(size_t)(k2 ? s2 : wid) * 16 + q];
        uint2 v3 = t2[(size_t)(k3 ? s3 : wid) * 16 + q];
        if (k0) {
            a[0] += bflo(v0.x); a[1] += bfhi(v0.x);
            a[2] += bflo(v0.y); a[3] += bfhi(v0.y);
        }
        if (k1) {
            a[0] += bflo(v1.x); a[1] += bfhi(v1.x);
            a[2] += bflo(v1.y); a[3] += bfhi(v1.y);
        }
        if (k2) {
            a[0] += bflo(v2.x); a[1] += bfhi(v2.x);
            a[2] += bflo(v2.y); a[3] += bfhi(v2.y);
        }
        if (k3) {
            a[0] += bflo(v3.x); a[1] += bfhi(v3.x);
            a[2] += bflo(v3.y); a[3] += bfhi(v3.y);
        }
    }
    for (int base = e0 + 32; base < e1; base += 2) {   // deg>32 tail (rare)
        int ee = base + g;
        if (ee < e1) {
            int s = col[ee];
            uint2 v = t2[(size_t)s * 16 + q];
            a[0] += bflo(v.x); a[1] += bfhi(v.x);
            a[2] += bflo(v.y); a[3] += bfhi(v.y);
        }
    }
    if (g == 0) {
        a[0] += bflo(selfv.x); a[1] += bfhi(selfv.x);
        a[2] += bflo(selfv.y); a[3] += bfhi(selfv.y);
    }
#pragma unroll
    for (int j = 0; j < 4; j++) a[j] += __shfl_xor(a[j], 16);
    if (g == 0) {
        float di = dinv[wid];
        float4 b4 = reinterpret_cast<const float4*>(bias)[q];
        float r0 = fmaxf(di * a[0] + b4.x, 0.f);
        float r1 = fmaxf(di * a[1] + b4.y, 0.f);
        float r2 = fmaxf(di * a[2] + b4.z, 0.f);
        float r3 = fmaxf(di * a[3] + b4.w, 0.f);
        if (OUT_BF16) {
            uint2 o;
            o.x = f2bf(r0) | (f2bf(r1) << 16);
            o.y = f2bf(r2) | (f2bf(r3) << 16);
            ((uint2*)out)[(size_t)wid * 16 + q] = o;
        } else {
            ((float4*)out)[(size_t)wid * 16 + q] = (float4){r0, r1, r2, r3};
        }
    }
}

// ---------------- launch ----------------

extern "C" void kernel_launch(void* const* d_in, const int* in_sizes, int n_in,
                              void* d_out, int out_size, void* d_ws, size_t ws_size,
                              hipStream_t stream) {
    const float* x = (const float*)d_in[0];
    const int* ei = (const int*)d_in[1];
    const int4* src4 = (const int4*)ei;
    const int4* dst4 = (const int4*)(ei + N_EDGES);
    const float* bn0_g = (const float*)d_in[2];
    const float* bn0_b = (const float*)d_in[3];
    const float* W0 = (const float*)d_in[4];
    const float* b0 = (const float*)d_in[5];
    const float* bns_g = (const float*)d_in[6];
    const float* bns_b = (const float*)d_in[7];
    const float* Ws = (const float*)d_in[8];
    const float* bs = (const float*)d_in[9];
    float* out = (float*)d_out;
    char* ws = (char*)d_ws;

    // workspace layout (bytes); xb dead after k_csr_gemm0 -> h1 and tbuf alias its halves
    float*  dinv    = (float*)(ws + 0);          //   400,128
    int*    row_ptr = (int*)(ws + 400128);       //   400,384
    int*    col     = (int*)(ws + 800512);       // 4,800,000
    int*    cursor  = (int*)(ws + 5600512);      //     1,600
    float*  sums    = (float*)(ws + 5602112);    //     2,560
    int*    bktBase = (int*)(ws + 5604672);      //     1,600
    ushort* wtg     = (ushort*)(ws + 5606272);   //    40,960
    int*    pairs   = (int*)(ws + 5647232);      //  6,406,144
    ushort* h0      = (ushort*)(ws + 12053376);  // 12,800,000
    ushort* xb      = (ushort*)(ws + 24853376);  // 25,600,000
    ushort* h1      = (ushort*)(ws + 24853376);  // 12,800,000 (aliases xb lower half)
    ushort* tbuf    = (ushort*)(ws + 37653376);  // 12,800,000 (aliases xb upper half) -> 50.5MB
    ushort* h2      = h0;                        // h0 dead after gemm_t1
    float* sums0 = sums;          // 256 floats (IN_F)
    float* sums1 = sums + 256;    // 128
    float* sums2 = sums + 384;    // 128
    float* sums3 = sums + 512;    // 128
    const ushort* wt1 = wtg + 8192;
    const ushort* wt2 = wtg + 8192 + 4096;
    const ushort* wt3 = wtg + 8192 + 8192;

    hipMemsetAsync(cursor, 0, 1600 + 640 * sizeof(float), stream);

    // ---- K_B (512 thr): bucket scatter || stats(x)+xb || Wt prep ----
    k_bucket_stats<<<NBB + SB + 1, 512, 0, stream>>>(src4, dst4, cursor, pairs,
                                                     (const float4*)x, (uint2*)xb, sums0,
                                                     W0, Ws, wtg);
    k_scan_bkt<<<1, 512, 0, stream>>>(cursor, bktBase, row_ptr);

    // ---- fused: CSR finalize || gemm0 ----
    k_csr_gemm0<<<NBKT + GEMM_B, 256, 0, stream>>>(pairs, cursor, bktBase, row_ptr, dinv,
                                                   col, xb, wtg, sums0, bn0_g, bn0_b, b0, h0);

    // ---- layer 1 ----
    k_stats_h<<<400, 256, 0, stream>>>((const uint4*)h0, sums1);
    k_gemm_t<<<GT_B, 256, 0, stream>>>(h0, wt1, sums1, bns_g, bns_b, dinv, tbuf);
    k_agg<true><<<AGG_B, 256, 0, stream>>>((const uint2*)tbuf, row_ptr, col, dinv, bs, h1);

    // ---- layer 2 ----
    k_stats_h<<<400, 256, 0, stream>>>((const uint4*)h1, sums2);
    k_gemm_t<<<GT_B, 256, 0, stream>>>(h1, wt2, sums2, bns_g + HID, bns_b + HID, dinv, tbuf);
    k_agg<true><<<AGG_B, 256, 0, stream>>>((const uint2*)tbuf, row_ptr, col, dinv,
                                           bs + HID, h2);

    // ---- layer 3 (f32 out) ----
    k_stats_h<<<400, 256, 0, stream>>>((const uint4*)h2, sums3);
    k_gemm_t<<<GT_B, 256, 0, stream>>>(h2, wt3, sums3, bns_g + 2 * HID, bns_b + 2 * HID,
                                       dinv, tbuf);
    k_agg<false><<<AGG_B, 256, 0, stream>>>((const uint2*)tbuf, row_ptr, col, dinv,
                                            bs + 2 * HID, out);
}